// Round 5
// baseline (925.371 us; speedup 1.0000x reference)
//
#include <hip/hip_runtime.h>
#include <hip/hip_bf16.h>

typedef __bf16 bf16;
typedef __bf16 bf16x8 __attribute__((ext_vector_type(8)));
typedef float f32x4 __attribute__((ext_vector_type(4)));

#define NB   32768
#define EMB  768
#define MSUB 32
#define KC   256
#define DSUB 24

// ws layout (bytes):
//   [0,     768K )  cb_t  : fp32 [32][24][256]  (d-major, k contiguous)
//   [1M,  2.125M)  rot_bf: bf16 [768][768]
//   [4M,   100M )  xr    : fp32 [32768][768]    (natural layout)

__device__ __forceinline__ bf16x8 cvt8(float4 a, float4 b) {
    bf16x8 r;
    r[0] = (bf16)a.x; r[1] = (bf16)a.y; r[2] = (bf16)a.z; r[3] = (bf16)a.w;
    r[4] = (bf16)b.x; r[5] = (bf16)b.y; r[6] = (bf16)b.z; r[7] = (bf16)b.w;
    return r;
}

// ---------------------------------------------------------------- kernel 0
__global__ __launch_bounds__(256, 4)
void pq_prep(const float* __restrict__ cb, const float* __restrict__ rot,
             float* __restrict__ cb_t, bf16* __restrict__ rot_bf) {
    const int b = blockIdx.x;
    const int t = threadIdx.x;
    if (b < 288) {                       // rot: 768*768 = 288*2048
        const int o = b * 2048 + t * 8;
        float4 a0 = *(const float4*)(rot + o);
        float4 a1 = *(const float4*)(rot + o + 4);
        *(bf16x8*)(rot_bf + o) = cvt8(a0, a1);
    } else {                             // cb transpose: [m][k][d] -> [m][d][k]
        const int m = b - 288;           // 0..31, t = k
        const float* src = cb + (size_t)(m * KC + t) * DSUB;
        float v[24];
        #pragma unroll
        for (int i = 0; i < 6; ++i)
            *(float4*)(v + 4 * i) = *(const float4*)(src + 4 * i);
        #pragma unroll
        for (int d = 0; d < DSUB; ++d)
            cb_t[((size_t)m * DSUB + d) * KC + t] = v[d];
    }
}

// ---------------------------------------------------------------- kernel 1
// xr = x @ rot^T via swapped MFMA: D[j][row] = mfma(A=rot_frag, B=x_frag).
// Acc regs hold 4 CONSECUTIVE j per lane -> direct f32x4 stores.
__global__ __launch_bounds__(512, 3)
void pq_rot(const float* __restrict__ x, const bf16* __restrict__ rot_bf,
            float* __restrict__ xr) {
    __shared__ bf16 g_lds[96 * 32 * 8];   // x bf16 granules [e8][row][slot], 48 KiB

    const int tid  = threadIdx.x;
    const int w    = tid >> 6;
    const int lane = tid & 63;
    const int l15  = lane & 15;
    const int lg   = lane >> 4;
    const int rowbase = blockIdx.x * 32;

    // stage x -> bf16 granules (each element read from HBM exactly once)
    #pragma unroll
    for (int i = 0; i < 6; ++i) {
        const int oct = i * 512 + tid;
        const int row = oct & 31;
        const int e8  = oct >> 5;
        const float* xp = x + (size_t)(rowbase + row) * EMB + e8 * 8;
        *(bf16x8*)&g_lds[(e8 * 32 + row) * 8] =
            cvt8(*(const float4*)xp, *(const float4*)(xp + 4));
    }
    __syncthreads();

    f32x4 acc[2][6];
    #pragma unroll
    for (int rt = 0; rt < 2; ++rt)
        #pragma unroll
        for (int jt = 0; jt < 6; ++jt)
            acc[rt][jt] = (f32x4){0.f, 0.f, 0.f, 0.f};

    const int jbase = w * 96;
    #pragma unroll 2
    for (int e0 = 0; e0 < EMB; e0 += 32) {
        bf16x8 xfrag[2];
        #pragma unroll
        for (int rt = 0; rt < 2; ++rt)
            xfrag[rt] = *(const bf16x8*)&g_lds[(((e0 >> 3) + lg) * 32 + rt * 16 + l15) * 8];
        #pragma unroll
        for (int jt = 0; jt < 6; ++jt) {
            const bf16* bp = rot_bf + (size_t)(jbase + jt * 16 + l15) * EMB + e0 + lg * 8;
            bf16x8 rotfrag = *(const bf16x8*)bp;
            acc[0][jt] = __builtin_amdgcn_mfma_f32_16x16x32_bf16(rotfrag, xfrag[0], acc[0][jt], 0, 0, 0);
            acc[1][jt] = __builtin_amdgcn_mfma_f32_16x16x32_bf16(rotfrag, xfrag[1], acc[1][jt], 0, 0, 0);
        }
    }

    // epilogue: acc[rt][jt] reg r = xr[rowbase+rt*16+l15][jbase+jt*16+lg*4+r]
    #pragma unroll
    for (int rt = 0; rt < 2; ++rt) {
        #pragma unroll
        for (int jt = 0; jt < 6; ++jt) {
            float* p = xr + (size_t)(rowbase + rt * 16 + l15) * EMB
                          + jbase + jt * 16 + lg * 4;
            *(f32x4*)p = acc[rt][jt];
        }
    }
}

// ---------------------------------------------------------------- kernel 2
// scores via pure VALU, k-quadrant split. Lane owns k = q*64+lane.
// Per (m,q): cbv[24] scalar VGPRs; xs rows double-buffered broadcast loads.
// Stores: 256 B aligned per instr (2 full 128 B lines) -> no amplification.
// VGPR ~ 24(cb) + 48(xs x2) + misc ~ 85  => fits 128 cap, no spill.
__global__ __launch_bounds__(512, 4)
void pq_scores(const float* __restrict__ xr, const float* __restrict__ cb_t,
               float* __restrict__ out) {
    const int tid  = threadIdx.x;
    const int lane = tid & 63;
    const int w    = tid >> 6;
    const int rowbase = blockIdx.x * 32;

    #pragma unroll 1
    for (int mm = 0; mm < 4; ++mm) {
        const int m = (w << 2) + mm;
        const float* xbase = xr + (size_t)rowbase * EMB + m * DSUB;

        #pragma unroll 1
        for (int q = 0; q < 4; ++q) {
            // codebook column chunk: cbv[d] = cb_t[m][d][q*64+lane]
            float cbv[DSUB];
            const float* cbp = cb_t + (size_t)m * DSUB * KC + q * 64 + lane;
            #pragma unroll
            for (int d = 0; d < DSUB; ++d)
                cbv[d] = cbp[d * KC];

            float* outq = out + ((size_t)rowbase * MSUB + m) * KC + q * 64 + lane;

            f32x4 xa[6], xb[6];
            auto loadrow = [&](int r, f32x4* xv) {
                const float* p = xbase + (size_t)r * EMB;
                #pragma unroll
                for (int i = 0; i < 6; ++i) xv[i] = *(const f32x4*)(p + 4 * i);
            };
            auto comprow = [&](int r, const f32x4* xv) {
                float acc = 0.f;
                #pragma unroll
                for (int i = 0; i < 6; ++i)
                    #pragma unroll
                    for (int dd = 0; dd < 4; ++dd)
                        acc = fmaf(cbv[i * 4 + dd], xv[i][dd], acc);
                __builtin_nontemporal_store(acc, outq + (size_t)r * (MSUB * KC));
            };

            loadrow(0, xa);
            loadrow(1, xb);
            #pragma unroll 1
            for (int r = 0; r < 32; r += 2) {
                comprow(r, xa);
                if (r + 2 < 32) loadrow(r + 2, xa);
                comprow(r + 1, xb);
                if (r + 3 < 32) loadrow(r + 3, xb);
            }
        }
    }
}

extern "C" void kernel_launch(void* const* d_in, const int* in_sizes, int n_in,
                              void* d_out, int out_size, void* d_ws, size_t ws_size,
                              hipStream_t stream) {
    const float* x   = (const float*)d_in[0];   // [32768, 768]
    const float* cbk = (const float*)d_in[1];   // [32, 256, 24]
    const float* rot = (const float*)d_in[2];   // [768, 768]
    float* out = (float*)d_out;                 // [32768, 32, 256]

    char* ws = (char*)d_ws;
    float* cb_t   = (float*)(ws);
    bf16*  rot_bf = (bf16*)(ws + (1u << 20));
    float* xr     = (float*)(ws + (4u << 20));

    hipLaunchKernelGGL(pq_prep,   dim3(320),  dim3(256), 0, stream, cbk, rot, cb_t, rot_bf);
    hipLaunchKernelGGL(pq_rot,    dim3(1024), dim3(512), 0, stream, x, rot_bf, xr);
    hipLaunchKernelGGL(pq_scores, dim3(1024), dim3(512), 0, stream, xr, cb_t, out);
}

// Round 6
// 479.054 us; speedup vs baseline: 1.9317x; 1.9317x over previous
//
#include <hip/hip_runtime.h>
#include <hip/hip_bf16.h>

typedef __bf16 bf16;
typedef __bf16 bf16x8 __attribute__((ext_vector_type(8)));
typedef float f32x4 __attribute__((ext_vector_type(4)));

#define NB   32768
#define EMB  768
#define MSUB 32
#define KC   256
#define DSUB 24

// ws layout (bytes):
//   [0,     768K )  cb_t  : fp32 [32][24][256]  (d-major, k contiguous)
//   [1M,  2.125M)  rot_bf: bf16 [768][768]
//   [4M,   100M )  xr    : fp32 [32768][768]    (natural layout)

__device__ __forceinline__ bf16x8 cvt8(float4 a, float4 b) {
    bf16x8 r;
    r[0] = (bf16)a.x; r[1] = (bf16)a.y; r[2] = (bf16)a.z; r[3] = (bf16)a.w;
    r[4] = (bf16)b.x; r[5] = (bf16)b.y; r[6] = (bf16)b.z; r[7] = (bf16)b.w;
    return r;
}

// ---------------------------------------------------------------- kernel 0
__global__ __launch_bounds__(256, 4)
void pq_prep(const float* __restrict__ cb, const float* __restrict__ rot,
             float* __restrict__ cb_t, bf16* __restrict__ rot_bf) {
    const int b = blockIdx.x;
    const int t = threadIdx.x;
    if (b < 288) {                       // rot: 768*768 = 288*2048
        const int o = b * 2048 + t * 8;
        float4 a0 = *(const float4*)(rot + o);
        float4 a1 = *(const float4*)(rot + o + 4);
        *(bf16x8*)(rot_bf + o) = cvt8(a0, a1);
    } else {                             // cb transpose: [m][k][d] -> [m][d][k]
        const int m = b - 288;           // 0..31, t = k
        const float* src = cb + (size_t)(m * KC + t) * DSUB;
        float v[24];
        #pragma unroll
        for (int i = 0; i < 6; ++i)
            *(float4*)(v + 4 * i) = *(const float4*)(src + 4 * i);
        #pragma unroll
        for (int d = 0; d < DSUB; ++d)
            cb_t[((size_t)m * DSUB + d) * KC + t] = v[d];
    }
}

// ---------------------------------------------------------------- kernel 1
// xr = x @ rot^T via swapped MFMA: D[j][row] = mfma(A=rot_frag, B=x_frag).
// Acc regs hold 4 CONSECUTIVE j per lane -> direct f32x4 stores.
__global__ __launch_bounds__(512, 3)
void pq_rot(const float* __restrict__ x, const bf16* __restrict__ rot_bf,
            float* __restrict__ xr) {
    __shared__ bf16 g_lds[96 * 32 * 8];   // x bf16 granules [e8][row][slot], 48 KiB

    const int tid  = threadIdx.x;
    const int w    = tid >> 6;
    const int lane = tid & 63;
    const int l15  = lane & 15;
    const int lg   = lane >> 4;
    const int rowbase = blockIdx.x * 32;

    // stage x -> bf16 granules (each element read from HBM exactly once)
    #pragma unroll
    for (int i = 0; i < 6; ++i) {
        const int oct = i * 512 + tid;
        const int row = oct & 31;
        const int e8  = oct >> 5;
        const float* xp = x + (size_t)(rowbase + row) * EMB + e8 * 8;
        *(bf16x8*)&g_lds[(e8 * 32 + row) * 8] =
            cvt8(*(const float4*)xp, *(const float4*)(xp + 4));
    }
    __syncthreads();

    f32x4 acc[2][6];
    #pragma unroll
    for (int rt = 0; rt < 2; ++rt)
        #pragma unroll
        for (int jt = 0; jt < 6; ++jt)
            acc[rt][jt] = (f32x4){0.f, 0.f, 0.f, 0.f};

    const int jbase = w * 96;
    #pragma unroll 2
    for (int e0 = 0; e0 < EMB; e0 += 32) {
        bf16x8 xfrag[2];
        #pragma unroll
        for (int rt = 0; rt < 2; ++rt)
            xfrag[rt] = *(const bf16x8*)&g_lds[(((e0 >> 3) + lg) * 32 + rt * 16 + l15) * 8];
        #pragma unroll
        for (int jt = 0; jt < 6; ++jt) {
            const bf16* bp = rot_bf + (size_t)(jbase + jt * 16 + l15) * EMB + e0 + lg * 8;
            bf16x8 rotfrag = *(const bf16x8*)bp;
            acc[0][jt] = __builtin_amdgcn_mfma_f32_16x16x32_bf16(rotfrag, xfrag[0], acc[0][jt], 0, 0, 0);
            acc[1][jt] = __builtin_amdgcn_mfma_f32_16x16x32_bf16(rotfrag, xfrag[1], acc[1][jt], 0, 0, 0);
        }
    }

    // epilogue: acc[rt][jt] reg r = xr[rowbase+rt*16+l15][jbase+jt*16+lg*4+r]
    #pragma unroll
    for (int rt = 0; rt < 2; ++rt) {
        #pragma unroll
        for (int jt = 0; jt < 6; ++jt) {
            float* p = xr + (size_t)(rowbase + rt * 16 + l15) * EMB
                          + jbase + jt * 16 + lg * 4;
            *(f32x4*)p = acc[rt][jt];
        }
    }
}

// ---------------------------------------------------------------- kernel 2
// scores, pure VALU. Lane owns k = 4*lane..4*lane+3 -> each (row,m) 1 KiB
// output line is written WHOLE by a single f32x4 wave-store (full lines,
// zero partial-line HBM traffic). Waves sweep m = mm*8 + w so a block's 8
// waves cover 8 consecutive m (8 KiB dense per row); XCD-bijective block
// swizzle keeps each XCD's write front in a contiguous 4096-row band.
__global__ __launch_bounds__(512, 2)
void pq_scores(const float* __restrict__ xr, const float* __restrict__ cb_t,
               float* __restrict__ out) {
    const int tid  = threadIdx.x;
    const int lane = tid & 63;
    const int w    = tid >> 6;

    // bijective XCD swizzle: 1024 blocks, 8 XCDs, 128 contiguous per XCD
    const int bid  = (int)blockIdx.x;
    const int swz  = (bid & 7) * 128 + (bid >> 3);
    const int rowbase = swz * 32;

    #pragma unroll 1
    for (int mm = 0; mm < 4; ++mm) {
        const int m = mm * 8 + w;

        // cbv[d][kk] = cb_t[m][d][4*lane+kk] : 96 VGPRs, L2-resident source
        f32x4 cbv[DSUB];
        const float* cbp = cb_t + (size_t)m * (DSUB * KC) + 4 * lane;
        #pragma unroll
        for (int d = 0; d < DSUB; ++d)
            cbv[d] = *(const f32x4*)(cbp + d * KC);

        const float* xbase = xr + (size_t)rowbase * EMB + m * DSUB;
        float* outm = out + ((size_t)rowbase * MSUB + m) * KC + 4 * lane;

        f32x4 xa[6], xb[6];
        auto loadrow = [&](int r, f32x4* xv) {
            const float* p = xbase + (size_t)r * EMB;
            #pragma unroll
            for (int i = 0; i < 6; ++i) xv[i] = *(const f32x4*)(p + 4 * i);
        };
        auto comprow = [&](int r, const f32x4* xv) {
            f32x4 acc = (f32x4){0.f, 0.f, 0.f, 0.f};
            #pragma unroll
            for (int i = 0; i < 6; ++i)
                #pragma unroll
                for (int dd = 0; dd < 4; ++dd)
                    acc += cbv[i * 4 + dd] * xv[i][dd];
            __builtin_nontemporal_store(acc, (f32x4*)(outm + (size_t)r * (MSUB * KC)));
        };

        loadrow(0, xa);
        loadrow(1, xb);
        #pragma unroll 1
        for (int r = 0; r < 32; r += 2) {
            comprow(r, xa);
            if (r + 2 < 32) loadrow(r + 2, xa);
            comprow(r + 1, xb);
            if (r + 3 < 32) loadrow(r + 3, xb);
        }
    }
}

extern "C" void kernel_launch(void* const* d_in, const int* in_sizes, int n_in,
                              void* d_out, int out_size, void* d_ws, size_t ws_size,
                              hipStream_t stream) {
    const float* x   = (const float*)d_in[0];   // [32768, 768]
    const float* cbk = (const float*)d_in[1];   // [32, 256, 24]
    const float* rot = (const float*)d_in[2];   // [768, 768]
    float* out = (float*)d_out;                 // [32768, 32, 256]

    char* ws = (char*)d_ws;
    float* cb_t   = (float*)(ws);
    bf16*  rot_bf = (bf16*)(ws + (1u << 20));
    float* xr     = (float*)(ws + (4u << 20));

    hipLaunchKernelGGL(pq_prep,   dim3(320),  dim3(256), 0, stream, cbk, rot, cb_t, rot_bf);
    hipLaunchKernelGGL(pq_rot,    dim3(1024), dim3(512), 0, stream, x, rot_bf, xr);
    hipLaunchKernelGGL(pq_scores, dim3(1024), dim3(512), 0, stream, xr, cb_t, out);
}